// Round 3
// baseline (121.397 us; speedup 1.0000x reference)
//
#include <hip/hip_runtime.h>

// ROI align-style pooling (bilinear), matches reference _pool_one_roi exactly.
// img: (1,128,128,1024) f32, rois: (1,256,4) f32 (x,y,w,h in pixels)
// out: (1,256,7,7,1024) f32
//
// R2: same as R1 (128 thr x 8 ch, NT stores) but using a clang ext_vector
//     float4 alias — __builtin_nontemporal_store rejects HIP_vector_type.

#define IMG_H 128
#define IMG_W 128
#define IMG_C 1024
#define POOLK 7

typedef float vfloat4 __attribute__((ext_vector_type(4)));

__device__ __forceinline__ vfloat4 lerp2d(vfloat4 v00, vfloat4 v01,
                                          vfloat4 v10, vfloat4 v11,
                                          float tx, float ty) {
  vfloat4 top = v00 + tx * (v01 - v00);
  vfloat4 bot = v10 + tx * (v11 - v10);
  return top + ty * (bot - top);
}

__global__ __launch_bounds__(128) void roi_pool_kernel(
    const float* __restrict__ img,
    const float* __restrict__ rois,
    float* __restrict__ out) {
  const int ix = blockIdx.x;   // 0..6
  const int iy = blockIdx.y;   // 0..6
  const int r  = blockIdx.z;   // 0..255

  // Uniform per-block geometry (redundant per-thread compute is cheap).
  const vfloat4 roi = *(const vfloat4*)(rois + (size_t)r * 4);

  // c = (roi * SCALE).astype(int32): non-negative, trunc == floor.
  const int x0 = (int)(roi.x * 0.0625f);
  const int y0 = (int)(roi.y * 0.0625f);
  const int w  = (int)(roi.z * 0.0625f);
  const int h  = (int)(roi.w * 0.0625f);

  // Match reference op order: (h_f / POOL) first, then multiply by i.
  const float sy = (float)iy * ((float)h / 7.0f);
  const float sx = (float)ix * ((float)w / 7.0f);
  const float fy = floorf(sy);
  const float fx = floorf(sx);
  const float ty = sy - fy;
  const float tx = sx - fx;
  const int y_lo = (int)fy;
  const int x_lo = (int)fx;
  const int y_hi = min(y_lo + 1, max(h - 1, 0));
  const int x_hi = min(x_lo + 1, max(w - 1, 0));
  const int gy0 = min(max(y0 + y_lo, 0), IMG_H - 1);
  const int gy1 = min(max(y0 + y_hi, 0), IMG_H - 1);
  const int gx0 = min(max(x0 + x_lo, 0), IMG_W - 1);
  const int gx1 = min(max(x0 + x_hi, 0), IMG_W - 1);

  const int c = threadIdx.x * 8;  // 128 threads x 8 channels = 1024

  const float* p00 = img + ((size_t)(gy0 * IMG_W + gx0)) * IMG_C + c;
  const float* p01 = img + ((size_t)(gy0 * IMG_W + gx1)) * IMG_C + c;
  const float* p10 = img + ((size_t)(gy1 * IMG_W + gx0)) * IMG_C + c;
  const float* p11 = img + ((size_t)(gy1 * IMG_W + gx1)) * IMG_C + c;

  // 8 independent 16B loads in flight.
  const vfloat4 a00 = *(const vfloat4*)(p00);
  const vfloat4 b00 = *(const vfloat4*)(p00 + 4);
  const vfloat4 a01 = *(const vfloat4*)(p01);
  const vfloat4 b01 = *(const vfloat4*)(p01 + 4);
  const vfloat4 a10 = *(const vfloat4*)(p10);
  const vfloat4 b10 = *(const vfloat4*)(p10 + 4);
  const vfloat4 a11 = *(const vfloat4*)(p11);
  const vfloat4 b11 = *(const vfloat4*)(p11 + 4);

  const vfloat4 oa = lerp2d(a00, a01, a10, a11, tx, ty);
  const vfloat4 ob = lerp2d(b00, b01, b10, b11, tx, ty);

  float* op = out + (((size_t)r * POOLK + iy) * POOLK + ix) * IMG_C + c;
  __builtin_nontemporal_store(oa, (vfloat4*)op);
  __builtin_nontemporal_store(ob, (vfloat4*)(op + 4));
}

extern "C" void kernel_launch(void* const* d_in, const int* in_sizes, int n_in,
                              void* d_out, int out_size, void* d_ws, size_t ws_size,
                              hipStream_t stream) {
  const float* img  = (const float*)d_in[0];   // 1*128*128*1024
  const float* rois = (const float*)d_in[1];   // 1*256*4
  float* out = (float*)d_out;                  // 1*256*7*7*1024

  dim3 grid(POOLK, POOLK, 256);
  dim3 block(128);
  roi_pool_kernel<<<grid, block, 0, stream>>>(img, rois, out);
}

// Round 4
// 120.100 us; speedup vs baseline: 1.0108x; 1.0108x over previous
//
#include <hip/hip_runtime.h>

// ROI align-style pooling (bilinear), matches reference _pool_one_roi exactly.
// img: (1,128,128,1024) f32, rois: (1,256,4) f32 (x,y,w,h in pixels)
// out: (1,256,7,7,1024) f32
//
// R3: A/B vs R2 — keep 128 thr x 8 ch (8 outstanding float4 loads),
//     REGULAR stores (NT stores suspected mild regression: bypassing L2
//     write-coalescing).

#define IMG_H 128
#define IMG_W 128
#define IMG_C 1024
#define POOLK 7

typedef float vfloat4 __attribute__((ext_vector_type(4)));

__device__ __forceinline__ vfloat4 lerp2d(vfloat4 v00, vfloat4 v01,
                                          vfloat4 v10, vfloat4 v11,
                                          float tx, float ty) {
  vfloat4 top = v00 + tx * (v01 - v00);
  vfloat4 bot = v10 + tx * (v11 - v10);
  return top + ty * (bot - top);
}

__global__ __launch_bounds__(128) void roi_pool_kernel(
    const float* __restrict__ img,
    const float* __restrict__ rois,
    float* __restrict__ out) {
  const int ix = blockIdx.x;   // 0..6
  const int iy = blockIdx.y;   // 0..6
  const int r  = blockIdx.z;   // 0..255

  // Uniform per-block geometry (redundant per-thread compute is cheap).
  const vfloat4 roi = *(const vfloat4*)(rois + (size_t)r * 4);

  // c = (roi * SCALE).astype(int32): non-negative, trunc == floor.
  const int x0 = (int)(roi.x * 0.0625f);
  const int y0 = (int)(roi.y * 0.0625f);
  const int w  = (int)(roi.z * 0.0625f);
  const int h  = (int)(roi.w * 0.0625f);

  // Match reference op order: (h_f / POOL) first, then multiply by i.
  const float sy = (float)iy * ((float)h / 7.0f);
  const float sx = (float)ix * ((float)w / 7.0f);
  const float fy = floorf(sy);
  const float fx = floorf(sx);
  const float ty = sy - fy;
  const float tx = sx - fx;
  const int y_lo = (int)fy;
  const int x_lo = (int)fx;
  const int y_hi = min(y_lo + 1, max(h - 1, 0));
  const int x_hi = min(x_lo + 1, max(w - 1, 0));
  const int gy0 = min(max(y0 + y_lo, 0), IMG_H - 1);
  const int gy1 = min(max(y0 + y_hi, 0), IMG_H - 1);
  const int gx0 = min(max(x0 + x_lo, 0), IMG_W - 1);
  const int gx1 = min(max(x0 + x_hi, 0), IMG_W - 1);

  const int c = threadIdx.x * 8;  // 128 threads x 8 channels = 1024

  const float* p00 = img + ((size_t)(gy0 * IMG_W + gx0)) * IMG_C + c;
  const float* p01 = img + ((size_t)(gy0 * IMG_W + gx1)) * IMG_C + c;
  const float* p10 = img + ((size_t)(gy1 * IMG_W + gx0)) * IMG_C + c;
  const float* p11 = img + ((size_t)(gy1 * IMG_W + gx1)) * IMG_C + c;

  // 8 independent 16B loads in flight.
  const vfloat4 a00 = *(const vfloat4*)(p00);
  const vfloat4 b00 = *(const vfloat4*)(p00 + 4);
  const vfloat4 a01 = *(const vfloat4*)(p01);
  const vfloat4 b01 = *(const vfloat4*)(p01 + 4);
  const vfloat4 a10 = *(const vfloat4*)(p10);
  const vfloat4 b10 = *(const vfloat4*)(p10 + 4);
  const vfloat4 a11 = *(const vfloat4*)(p11);
  const vfloat4 b11 = *(const vfloat4*)(p11 + 4);

  const vfloat4 oa = lerp2d(a00, a01, a10, a11, tx, ty);
  const vfloat4 ob = lerp2d(b00, b01, b10, b11, tx, ty);

  float* op = out + (((size_t)r * POOLK + iy) * POOLK + ix) * IMG_C + c;
  *(vfloat4*)op = oa;
  *(vfloat4*)(op + 4) = ob;
}

extern "C" void kernel_launch(void* const* d_in, const int* in_sizes, int n_in,
                              void* d_out, int out_size, void* d_ws, size_t ws_size,
                              hipStream_t stream) {
  const float* img  = (const float*)d_in[0];   // 1*128*128*1024
  const float* rois = (const float*)d_in[1];   // 1*256*4
  float* out = (float*)d_out;                  // 1*256*7*7*1024

  dim3 grid(POOLK, POOLK, 256);
  dim3 block(128);
  roi_pool_kernel<<<grid, block, 0, stream>>>(img, rois, out);
}